// Round 1
// baseline (114.937 us; speedup 1.0000x reference)
//
#include <hip/hip_runtime.h>
#include <math.h>

#define BATCH   256
#define IN_F    2048
#define OUT_F   256
#define KD      8
#define NCOL    2048    /* OUT_F*KD — T flattened is [IN_F][NCOL] row-major */
#define OSTRIDE 2304    /* IN_F + OUT_F */

// ---------------------------------------------------------------------------
// Kernel 1: M[b,c] = sum_i x[b,i] * W[i,c]   (W = T viewed as [2048][2048])
// BM=32, BN=64, BK=16, 256 threads, 2x4 thread tile.
// Grid: (NCOL/64, BATCH/32) = (32, 8) = 256 blocks -> one per CU.
// ---------------------------------------------------------------------------
__global__ __launch_bounds__(256)
void k_gemm(const float* __restrict__ X, const float* __restrict__ W,
            float* __restrict__ M) {
    __shared__ float As[16][33];   // [k][m], padded
    __shared__ float Bs[16][64];   // [k][n]

    const int t  = threadIdx.x;
    const int bn = blockIdx.x * 64;
    const int bm = blockIdx.y * 32;

    // A tile loaders: 32 rows x 16 k -> 512 elems, float2 per thread
    const int arow = t >> 3;          // 0..31
    const int acol = (t & 7) << 1;    // 0,2,...,14
    // B tile loaders: 16 k x 64 n -> 1024 elems, float4 per thread
    const int brow = t >> 4;          // 0..15
    const int bcol = (t & 15) << 2;   // 0..60

    const float* xp = X + (size_t)(bm + arow) * IN_F + acol;
    const float* wp = W + (size_t)brow * NCOL + bn + bcol;

    const int tm = (t >> 4) << 1;     // 0..30
    const int tn = (t & 15) << 2;     // 0..60

    float acc[2][4] = {{0.f, 0.f, 0.f, 0.f}, {0.f, 0.f, 0.f, 0.f}};

    for (int k0 = 0; k0 < IN_F; k0 += 16) {
        float2 av = *(const float2*)(xp + k0);
        float4 bv = *(const float4*)(wp + (size_t)k0 * NCOL);
        As[acol][arow]     = av.x;
        As[acol + 1][arow] = av.y;
        Bs[brow][bcol]     = bv.x;
        Bs[brow][bcol + 1] = bv.y;
        Bs[brow][bcol + 2] = bv.z;
        Bs[brow][bcol + 3] = bv.w;
        __syncthreads();
#pragma unroll
        for (int k = 0; k < 16; ++k) {
            float a0 = As[k][tm];
            float a1 = As[k][tm + 1];
            float b0 = Bs[k][tn];
            float b1 = Bs[k][tn + 1];
            float b2 = Bs[k][tn + 2];
            float b3 = Bs[k][tn + 3];
            acc[0][0] = fmaf(a0, b0, acc[0][0]);
            acc[0][1] = fmaf(a0, b1, acc[0][1]);
            acc[0][2] = fmaf(a0, b2, acc[0][2]);
            acc[0][3] = fmaf(a0, b3, acc[0][3]);
            acc[1][0] = fmaf(a1, b0, acc[1][0]);
            acc[1][1] = fmaf(a1, b1, acc[1][1]);
            acc[1][2] = fmaf(a1, b2, acc[1][2]);
            acc[1][3] = fmaf(a1, b3, acc[1][3]);
        }
        __syncthreads();
    }

    float* mp = M + (size_t)(bm + tm) * NCOL + bn + tn;
    mp[0] = acc[0][0]; mp[1] = acc[0][1]; mp[2] = acc[0][2]; mp[3] = acc[0][3];
    mp += NCOL;
    mp[0] = acc[1][0]; mp[1] = acc[1][1]; mp[2] = acc[1][2]; mp[3] = acc[1][3];
}

// ---------------------------------------------------------------------------
// Kernel 2: pairwise L1-exp reduction.
// One block per output feature o; thread j owns batch row j.
// o_b[j,o] = sum_i exp(-sum_k |M[i,o,k]-M[j,o,k]|) - 1
// ---------------------------------------------------------------------------
__global__ __launch_bounds__(256)
void k_pair(const float* __restrict__ M, float* __restrict__ out) {
    __shared__ float4 Ms[BATCH][2];   // 8 KB: the 256x8 slice for this o

    const int o = blockIdx.x;
    const int j = threadIdx.x;

    const float* mp = M + (size_t)j * NCOL + o * KD;
    float4 a = *(const float4*)(mp);
    float4 b = *(const float4*)(mp + 4);
    Ms[j][0] = a;
    Ms[j][1] = b;
    __syncthreads();

    const float m0 = a.x, m1 = a.y, m2 = a.z, m3 = a.w;
    const float m4 = b.x, m5 = b.y, m6 = b.z, m7 = b.w;

    float acc = 0.f;
    for (int i = 0; i < BATCH; ++i) {
        float4 u = Ms[i][0];   // broadcast read (all lanes same addr)
        float4 v = Ms[i][1];
        float norm = fabsf(u.x - m0) + fabsf(u.y - m1) +
                     fabsf(u.z - m2) + fabsf(u.w - m3) +
                     fabsf(v.x - m4) + fabsf(v.y - m5) +
                     fabsf(v.z - m6) + fabsf(v.w - m7);
        acc += __expf(-norm);
    }
    out[(size_t)j * OSTRIDE + IN_F + o] = acc - 1.0f;
}

// ---------------------------------------------------------------------------
// Kernel 3: copy x into out[:, 0:IN_F]
// ---------------------------------------------------------------------------
__global__ __launch_bounds__(256)
void k_copy(const float* __restrict__ X, float* __restrict__ out) {
    int idx = blockIdx.x * 256 + threadIdx.x;  // float4 index
    int e = idx << 2;                          // element index into x (flat)
    int b = e >> 11;                           // / IN_F
    int c = e & (IN_F - 1);
    *(float4*)(out + (size_t)b * OSTRIDE + c) = *(const float4*)(X + e);
}

extern "C" void kernel_launch(void* const* d_in, const int* in_sizes, int n_in,
                              void* d_out, int out_size, void* d_ws, size_t ws_size,
                              hipStream_t stream) {
    const float* x = (const float*)d_in[0];   // [256, 2048]
    const float* T = (const float*)d_in[1];   // [2048, 256, 8] == [2048][2048]
    float* out = (float*)d_out;               // [256, 2304]
    float* M = (float*)d_ws;                  // [256, 2048] scratch (2 MB)

    dim3 gg(NCOL / 64, BATCH / 32);
    k_gemm<<<gg, 256, 0, stream>>>(x, T, M);
    k_copy<<<(BATCH * IN_F / 4) / 256, 256, 0, stream>>>(x, out);
    k_pair<<<OUT_F, 256, 0, stream>>>(M, out);
}

// Round 2
// 54.259 us; speedup vs baseline: 2.1183x; 2.1183x over previous
//
#include <hip/hip_runtime.h>
#include <hip/hip_bf16.h>
#include <math.h>

#define BATCH   256
#define IN_F    2048
#define OUT_F   256
#define KD      8
#define NCOL    2048    /* OUT_F*KD */
#define OSTRIDE 2304    /* IN_F + OUT_F */

typedef float  f32x4  __attribute__((ext_vector_type(4)));
typedef short  bf16x8 __attribute__((ext_vector_type(8)));
typedef unsigned short u16;

// ws layout: [0,2MB) M fp32 [256][2048]; [2MB,10MB) Wt bf16 [2048][2048] ([n][k]);
//            [10MB,11MB) Xb bf16 [256][2048]
#define WT_OFF (2u << 20)
#define XB_OFF (10u << 20)

__device__ __forceinline__ u16 f2bf(float f) {
    unsigned u = __builtin_bit_cast(unsigned, f);
    u += 0x7fff + ((u >> 16) & 1);              // RNE
    return (u16)(u >> 16);
}

#define GLDS16(gp, lp) \
    __builtin_amdgcn_global_load_lds( \
        (const __attribute__((address_space(1))) void*)(gp), \
        (__attribute__((address_space(3))) void*)(lp), 16, 0, 0)

// ---------------------------------------------------------------------------
// Transpose + convert: Wt[n][k] = bf16(T[k][n]).  64x64 tiles, XOR-swizzled LDS.
// ---------------------------------------------------------------------------
__global__ __launch_bounds__(256)
void k_tconv(const float* __restrict__ T, u16* __restrict__ Wt) {
    __shared__ u16 L[64 * 64];
    const int t = threadIdx.x;
    const int kk0 = (blockIdx.x & 31) << 6;
    const int nn0 = (blockIdx.x >> 5) << 6;
#pragma unroll
    for (int it = 0; it < 4; ++it) {
        int kl = it * 16 + (t >> 4);
        int nl = (t & 15) * 4;
        float4 v = *(const float4*)(T + (size_t)(kk0 + kl) * NCOL + nn0 + nl);
        u16 h[4] = {f2bf(v.x), f2bf(v.y), f2bf(v.z), f2bf(v.w)};
#pragma unroll
        for (int j = 0; j < 4; ++j) {
            int n = nl + j;
            int byte = n * 128 + ((kl * 2) ^ ((n & 7) << 4));
            *(u16*)((char*)L + byte) = h[j];
        }
    }
    __syncthreads();
#pragma unroll
    for (int it = 0; it < 2; ++it) {
        int u = it * 256 + t;
        int n = u >> 3, c = u & 7;
        int byte = n * 128 + ((c * 16) ^ ((n & 7) << 4));
        float4 d = *(float4*)((char*)L + byte);
        *(float4*)(Wt + (size_t)(nn0 + n) * NCOL + kk0 + c * 8) = d;
    }
}

// ---------------------------------------------------------------------------
// X fp32 -> bf16
// ---------------------------------------------------------------------------
__global__ __launch_bounds__(256)
void k_xconv(const float* __restrict__ X, u16* __restrict__ Xb) {
    int i = (blockIdx.x * 256 + threadIdx.x) * 8;
    float4 a = *(const float4*)(X + i);
    float4 b = *(const float4*)(X + i + 4);
    u16 h[8] = {f2bf(a.x), f2bf(a.y), f2bf(a.z), f2bf(a.w),
                f2bf(b.x), f2bf(b.y), f2bf(b.z), f2bf(b.w)};
    *(float4*)(Xb + i) = *(float4*)h;
}

// ---------------------------------------------------------------------------
// MFMA GEMM: M[b][c] = sum_k Xb[b][k] * Wt[c][k].  BM=32 BN=64 BK=64.
// 256 blocks (XCD-grouped), 4 waves; global_load_lds w/ pre-swizzled source;
// double-buffered 2-phase.
// A/B operand layout (16x16x32 bf16): lane l holds row/col = l&15,
// k = (l>>4)*8 + j (8 contiguous).  C/D: col = l&15, row = (l>>4)*4 + reg
// [verified mapping per m89/m91].
// ---------------------------------------------------------------------------
__global__ __launch_bounds__(256)
void k_gemm(const u16* __restrict__ Xb, const u16* __restrict__ Wt,
            float* __restrict__ M) {
    __shared__ u16 As[2][32 * 64];
    __shared__ u16 Bs[2][64 * 64];
    const int t = threadIdx.x;
    const int l = t & 63, w = t >> 6;
    const int x = blockIdx.x & 7, y = blockIdx.x >> 3;
    const int mi = y >> 2, ni = x * 4 + (y & 3);   // same-ni blocks share an XCD
    const int bm = mi * 32, bn = ni * 64;
    const int wm = w >> 1, wn = w & 1;

    // --- staging addresses (source pre-swizzled; LDS linear) ---
    const int arow = w * 8 + (l >> 3);                 // local A row 0..31
    const u16* agp = Xb + (size_t)(bm + arow) * IN_F + (((l & 7) ^ (arow & 7)) * 8);
    const int brow0 = w * 16 + (l >> 3);               // local B rows
    const int brow1 = brow0 + 8;
    const u16* bgp0 = Wt + (size_t)(bn + brow0) * NCOL + (((l & 7) ^ (brow0 & 7)) * 8);
    const u16* bgp1 = Wt + (size_t)(bn + brow1) * NCOL + (((l & 7) ^ (brow1 & 7)) * 8);

    // --- fragment read offsets (XOR-swizzled) ---
    const int lm = l & 15, lq = l >> 4;
    const int ar = wm * 16 + lm;
    const int sA = (ar & 7) << 4;
    const int aoff0 = ar * 128 + ((lq * 16) ^ sA);
    const int aoff1 = ar * 128 + ((lq * 16 + 64) ^ sA);
    const int br0 = wn * 32 + lm;
    const int br1 = br0 + 16;
    const int sB = (br0 & 7) << 4;                     // (br1&7)==(br0&7)
    const int boff00 = br0 * 128 + ((lq * 16) ^ sB);
    const int boff01 = br0 * 128 + ((lq * 16 + 64) ^ sB);
    const int boff10 = br1 * 128 + ((lq * 16) ^ sB);
    const int boff11 = br1 * 128 + ((lq * 16 + 64) ^ sB);

#define STAGE(buf, k0) do { \
        GLDS16(agp + (k0),  &As[buf][w * 512]); \
        GLDS16(bgp0 + (k0), &Bs[buf][w * 1024]); \
        GLDS16(bgp1 + (k0), &Bs[buf][w * 1024 + 512]); \
    } while (0)

    f32x4 acc0 = {0.f, 0.f, 0.f, 0.f};
    f32x4 acc1 = {0.f, 0.f, 0.f, 0.f};

    STAGE(0, 0);
    __syncthreads();                    // compiler drains vmcnt before s_barrier
    for (int kt = 0; kt < 32; ++kt) {
        const int cur = kt & 1;
        if (kt + 1 < 32) STAGE(cur ^ 1, (kt + 1) * 64);
        const char* Ab = (const char*)As[cur];
        const char* Bb = (const char*)Bs[cur];
        bf16x8 a0  = *(const bf16x8*)(Ab + aoff0);
        bf16x8 a1  = *(const bf16x8*)(Ab + aoff1);
        bf16x8 b00 = *(const bf16x8*)(Bb + boff00);
        bf16x8 b01 = *(const bf16x8*)(Bb + boff01);
        bf16x8 b10 = *(const bf16x8*)(Bb + boff10);
        bf16x8 b11 = *(const bf16x8*)(Bb + boff11);
        acc0 = __builtin_amdgcn_mfma_f32_16x16x32_bf16(a0, b00, acc0, 0, 0, 0);
        acc0 = __builtin_amdgcn_mfma_f32_16x16x32_bf16(a1, b01, acc0, 0, 0, 0);
        acc1 = __builtin_amdgcn_mfma_f32_16x16x32_bf16(a0, b10, acc1, 0, 0, 0);
        acc1 = __builtin_amdgcn_mfma_f32_16x16x32_bf16(a1, b11, acc1, 0, 0, 0);
        __syncthreads();
    }
#undef STAGE

    const int om = bm + wm * 16 + lq * 4;
    const int on = bn + wn * 32 + lm;
#pragma unroll
    for (int r = 0; r < 4; ++r) {
        M[(size_t)(om + r) * NCOL + on]      = acc0[r];
        M[(size_t)(om + r) * NCOL + on + 16] = acc1[r];
    }
}

// ---------------------------------------------------------------------------
// Pairwise L1-exp reduction. One block per output feature o.
// ---------------------------------------------------------------------------
__global__ __launch_bounds__(256)
void k_pair(const float* __restrict__ M, float* __restrict__ out) {
    __shared__ float4 Ms[BATCH][2];
    const int o = blockIdx.x;
    const int j = threadIdx.x;
    const float* mp = M + (size_t)j * NCOL + o * KD;
    float4 a = *(const float4*)(mp);
    float4 b = *(const float4*)(mp + 4);
    Ms[j][0] = a;
    Ms[j][1] = b;
    __syncthreads();
    const float m0 = a.x, m1 = a.y, m2 = a.z, m3 = a.w;
    const float m4 = b.x, m5 = b.y, m6 = b.z, m7 = b.w;
    float acc = 0.f;
    for (int i = 0; i < BATCH; ++i) {
        float4 u = Ms[i][0];
        float4 v = Ms[i][1];
        float norm = fabsf(u.x - m0) + fabsf(u.y - m1) +
                     fabsf(u.z - m2) + fabsf(u.w - m3) +
                     fabsf(v.x - m4) + fabsf(v.y - m5) +
                     fabsf(v.z - m6) + fabsf(v.w - m7);
        acc += __expf(-norm);
    }
    out[(size_t)j * OSTRIDE + IN_F + o] = acc - 1.0f;
}

// ---------------------------------------------------------------------------
// Copy x into out[:, 0:IN_F]
// ---------------------------------------------------------------------------
__global__ __launch_bounds__(256)
void k_copy(const float* __restrict__ X, float* __restrict__ out) {
    int idx = blockIdx.x * 256 + threadIdx.x;
    int e = idx << 2;
    int b = e >> 11;
    int c = e & (IN_F - 1);
    *(float4*)(out + (size_t)b * OSTRIDE + c) = *(const float4*)(X + e);
}

extern "C" void kernel_launch(void* const* d_in, const int* in_sizes, int n_in,
                              void* d_out, int out_size, void* d_ws, size_t ws_size,
                              hipStream_t stream) {
    const float* x = (const float*)d_in[0];   // [256, 2048]
    const float* T = (const float*)d_in[1];   // [2048][2048] flattened
    float* out = (float*)d_out;               // [256, 2304]
    char* ws = (char*)d_ws;
    float* M  = (float*)ws;
    u16*  Wt  = (u16*)(ws + WT_OFF);
    u16*  Xb  = (u16*)(ws + XB_OFF);

    k_tconv<<<1024, 256, 0, stream>>>(T, Wt);
    k_xconv<<<256, 256, 0, stream>>>(x, Xb);
    k_copy<<<512, 256, 0, stream>>>(x, out);
    k_gemm<<<256, 256, 0, stream>>>(Xb, Wt, M);
    k_pair<<<256, 256, 0, stream>>>(M, out);
}

// Round 3
// 34.804 us; speedup vs baseline: 3.3024x; 1.5590x over previous
//
#include <hip/hip_runtime.h>
#include <math.h>

#define BATCH   256
#define IN_F    2048
#define OUT_F   256
#define KD      8
#define NCOL    2048    /* OUT_F*KD */
#define OSTRIDE 2304    /* IN_F + OUT_F */
#define LOG2E   1.4426950408889634f

typedef float  f32x4  __attribute__((ext_vector_type(4)));
typedef short  bf16x8 __attribute__((ext_vector_type(8)));
typedef unsigned short u16;

// ws layout:
//   [0, 2MB)   Mp  fp32 [256 o][256 j][8 k]   (pair-friendly)
//   [2, 10MB)  Wt  bf16 fragment-tiled: [nt(128)][kc(256)][n16(16)][8]
//   [10,11MB)  Xb  bf16 fragment-tiled: [rt(16)][kc(256)][r16(16)][8] (pre-scaled by log2e)
#define WT_OFF (2u << 20)
#define XB_OFF (10u << 20)

__device__ __forceinline__ u16 f2bf(float f) {
    unsigned u = __builtin_bit_cast(unsigned, f);
    u += 0x7fff + ((u >> 16) & 1);              // RNE
    return (u16)(u >> 16);
}

// ---------------------------------------------------------------------------
// Fused prep: T transpose+convert (tiled), X convert (tiled, *log2e), X copy.
// Grid 1024 x 256 threads, no LDS.
// ---------------------------------------------------------------------------
__global__ __launch_bounds__(256)
void k_prep(const float* __restrict__ X, const float* __restrict__ T,
            u16* __restrict__ Wt, u16* __restrict__ Xb,
            float* __restrict__ out) {
    const int b = blockIdx.x, t = threadIdx.x;
    if (b < 256) {
        // --- tconv: T[k][n] fp32 -> Wt[nt][kc][n16][8] bf16 ---
        const int n  = (b & 7) * 256 + t;       // thread owns column n
        const int kg = b >> 3;                  // 64-k group
        const int nt = n >> 4, n16 = n & 15;
#pragma unroll
        for (int kc = 0; kc < 8; ++kc) {
            const int kb = kg * 64 + kc * 8;
            u16 h[8];
#pragma unroll
            for (int r = 0; r < 8; ++r)
                h[r] = f2bf(T[(size_t)(kb + r) * NCOL + n]);   // 1KB-coalesced per r
            *(float4*)(Wt + ((size_t)(nt * 256 + kg * 8 + kc) * 16 + n16) * 8) =
                *(float4*)h;
        }
    } else if (b < 512) {
        // --- xconv: X fp32 -> Xb[rt][kc][r16][8] bf16, scaled by log2e ---
        const int g   = b - 256;
        const int rt  = g >> 4;
        const int kc  = (g & 15) * 16 + (t & 15);
        const int r16 = t >> 4;
        const float* src = X + (size_t)(rt * 16 + r16) * IN_F + kc * 8;
        float4 v0 = *(const float4*)src;
        float4 v1 = *(const float4*)(src + 4);
        u16 h[8] = {f2bf(v0.x * LOG2E), f2bf(v0.y * LOG2E),
                    f2bf(v0.z * LOG2E), f2bf(v0.w * LOG2E),
                    f2bf(v1.x * LOG2E), f2bf(v1.y * LOG2E),
                    f2bf(v1.z * LOG2E), f2bf(v1.w * LOG2E)};
        *(float4*)(Xb + ((size_t)(rt * 256 + kc) * 16 + r16) * 8) = *(float4*)h;
    } else {
        // --- copy x into out[:, 0:IN_F] ---
        const int idx = (b - 512) * 256 + t;
        const int e = idx << 2;
        const int r = e >> 11, c = e & (IN_F - 1);
        *(float4*)(out + (size_t)r * OSTRIDE + c) = *(const float4*)(X + e);
    }
}

// ---------------------------------------------------------------------------
// MFMA GEMM, no LDS, no barriers. BM=32 BN=64, 256 blocks x 8 waves.
// Each wave computes one 16x16 tile; fragments loaded directly from the
// tiled global layouts (lane-linear 1KB per wave-load, L1 dedups sharing).
// Mp[o][j][k] = sum_k Xb * Wt  (already scaled by log2e).
// C/D layout: col = l&15, row = (l>>4)*4 + r   [m89/m91].
// ---------------------------------------------------------------------------
__global__ __launch_bounds__(512)
void k_gemm(const u16* __restrict__ Xb, const u16* __restrict__ Wt,
            float* __restrict__ Mp) {
    const int t = threadIdx.x, l = t & 63, w = t >> 6;
    const int x = blockIdx.x & 7, y = blockIdx.x >> 3;
    const int bmti = y & 7;              // row-tile-pair: rows bmti*32..
    const int bnti = x * 4 + (y >> 3);   // col-64 tile; same-bnti blocks share an XCD
    const int rt = bmti * 2 + (w & 1);   // 16-row tile 0..15
    const int nt = bnti * 4 + (w >> 1);  // 16-col tile 0..127

    const int lane_off = (l >> 4) * 128 + (l & 15) * 8;
    const u16* ap = Xb + (size_t)rt * 32768 + lane_off;
    const u16* bp = Wt + (size_t)nt * 32768 + lane_off;

    f32x4 acc = {0.f, 0.f, 0.f, 0.f};
#pragma unroll 8
    for (int s = 0; s < 64; ++s) {
        bf16x8 a = *(const bf16x8*)(ap + s * 512);
        bf16x8 bb = *(const bf16x8*)(bp + s * 512);
        acc = __builtin_amdgcn_mfma_f32_16x16x32_bf16(a, bb, acc, 0, 0, 0);
    }

    const int c = nt * 16 + (l & 15);    // global column
    const int o = c >> 3, k = c & 7;
    const int j0 = rt * 16 + (l >> 4) * 4;
    float* dst = Mp + ((size_t)o * 256 + j0) * 8 + k;
#pragma unroll
    for (int r = 0; r < 4; ++r) dst[r * 8] = acc[r];
}

// ---------------------------------------------------------------------------
// Pairwise L1-exp2 reduction. Block = feature o; 512 threads = (i-half, j).
// ---------------------------------------------------------------------------
__global__ __launch_bounds__(512)
void k_pair(const float* __restrict__ Mp, float* __restrict__ out) {
    __shared__ float4 Ms[BATCH][2];   // 8 KB slice
    __shared__ float  Ps[512];
    const int o = blockIdx.x, t = threadIdx.x;
    const int j = t & 255, h = t >> 8;

    ((float4*)Ms)[t] = ((const float4*)(Mp + (size_t)o * 2048))[t];
    __syncthreads();

    const float4 a = Ms[j][0], b = Ms[j][1];
    const float m0 = a.x, m1 = a.y, m2 = a.z, m3 = a.w;
    const float m4 = b.x, m5 = b.y, m6 = b.z, m7 = b.w;

    float acc = 0.f;
    const int i0 = h * 128;
    for (int i = 0; i < 128; ++i) {
        float4 u = Ms[i0 + i][0];       // broadcast reads
        float4 v = Ms[i0 + i][1];
        float norm = fabsf(u.x - m0) + fabsf(u.y - m1) +
                     fabsf(u.z - m2) + fabsf(u.w - m3) +
                     fabsf(v.x - m4) + fabsf(v.y - m5) +
                     fabsf(v.z - m6) + fabsf(v.w - m7);
        acc += exp2f(-norm);            // inputs pre-scaled by log2e
    }
    Ps[t] = acc;
    __syncthreads();
    if (t < 256)
        out[(size_t)t * OSTRIDE + IN_F + o] = Ps[t] + Ps[t + 256] - 1.0f;
}

extern "C" void kernel_launch(void* const* d_in, const int* in_sizes, int n_in,
                              void* d_out, int out_size, void* d_ws, size_t ws_size,
                              hipStream_t stream) {
    const float* x = (const float*)d_in[0];   // [256, 2048]
    const float* T = (const float*)d_in[1];   // [2048][2048] flattened
    float* out = (float*)d_out;               // [256, 2304]
    char* ws = (char*)d_ws;
    float* Mp = (float*)ws;
    u16*  Wt  = (u16*)(ws + WT_OFF);
    u16*  Xb  = (u16*)(ws + XB_OFF);

    k_prep<<<1024, 256, 0, stream>>>(x, T, Wt, Xb, out);
    k_gemm<<<256, 512, 0, stream>>>(Xb, Wt, Mp);
    k_pair<<<256, 512, 0, stream>>>(Mp, out);
}